// Round 1
// baseline (260.140 us; speedup 1.0000x reference)
//
#include <hip/hip_runtime.h>
#include <hip/hip_bf16.h>

#define NN 8192
#define L2E 1.44269504088896340736f
#define TWO_PI 6.28318530717958647693f

typedef _Float16 h8 __attribute__((ext_vector_type(8)));
typedef float f32x4 __attribute__((ext_vector_type(4)));

// ---------------------------------------------------------------------------
// Kernel A: eta/phi extraction + H1 = relu(x@W1 + b1), stored f32 row-major
// and f16 transposed [64][8192] for MFMA B-operand loads.
// ---------------------------------------------------------------------------
__global__ __launch_bounds__(256) void prep_kernel(
    const float* __restrict__ x, const float* __restrict__ W1,
    const float* __restrict__ b1,
    float* __restrict__ eta, float* __restrict__ phi,
    float* __restrict__ H1, _Float16* __restrict__ HT1)
{
  __shared__ float sW[7 * 64];
  __shared__ float sb[64];
  __shared__ float T[64][65];
  const int t = threadIdx.x;
  for (int k = t; k < 448; k += 256) sW[k] = W1[k];
  if (t < 64) sb[t] = b1[t];
  const int i0 = blockIdx.x * 64;
  const int r = t >> 2;       // 0..63 row within block
  const int q = t & 3;        // 0..3 col quarter
  const int i = i0 + r;
  float xv[7];
#pragma unroll
  for (int k = 0; k < 7; k++) xv[k] = x[i * 7 + k];
  if (q == 0) { eta[i] = xv[1]; phi[i] = xv[2]; }
  __syncthreads();
#pragma unroll
  for (int cc = 0; cc < 16; cc++) {
    const int n = q * 16 + cc;
    float h = sb[n];
#pragma unroll
    for (int k = 0; k < 7; k++) h = fmaf(xv[k], sW[k * 64 + n], h);
    T[r][n] = fmaxf(h, 0.f);
  }
  __syncthreads();
  for (int e = t; e < 4096; e += 256) H1[i0 * 64 + e] = T[e >> 6][e & 63];
  {
    const int n = t >> 2;
    const int ic = (t & 3) * 16;
    h8 v0, v1;
#pragma unroll
    for (int s = 0; s < 8; s++) v0[s] = (_Float16)T[ic + s][n];
#pragma unroll
    for (int s = 0; s < 8; s++) v1[s] = (_Float16)T[ic + 8 + s][n];
    *(h8*)(HT1 + n * NN + i0 + ic) = v0;
    *(h8*)(HT1 + n * NN + i0 + ic + 8) = v1;
  }
}

// ---------------------------------------------------------------------------
// Fused "attention" pass: Y[i][:] = sum_j exp(exp(-a*dR2_ij)-1) * H[j][:]
// and (layer 1 only) l[i] = sum_j exp(exp(-a*dR2_ij)-1).
// Block = 256 thr = 4 waves, all on the same 16 rows; waves interleave over
// j-chunks of 32; scores generated in registers directly in MFMA A-layout
// (A[m=lane&15][k=(lane>>4)*8+t]); Hᵀ f16 16B loads give B-frags.
// ---------------------------------------------------------------------------
template <bool NEED_L>
__global__ __launch_bounds__(256) void attn_pass(
    const float* __restrict__ eta, const float* __restrict__ phi,
    const _Float16* __restrict__ HT, const float* __restrict__ alpha,
    float* __restrict__ Y, float* __restrict__ lsum_out)
{
  const int tid = threadIdx.x;
  const int w = tid >> 6;          // wave 0..3
  const int lane = tid & 63;
  const int m = lane & 15;         // row within 16-row tile / B n-index
  const int g = lane >> 4;         // k-group 0..3
  const int i_base = blockIdx.x << 4;
  const float my_eta = eta[i_base + m];
  const float my_phi = phi[i_base + m];
  const float c1 = -alpha[0] * L2E;

  f32x4 acc0 = {0.f, 0.f, 0.f, 0.f}, acc1 = {0.f, 0.f, 0.f, 0.f};
  f32x4 acc2 = {0.f, 0.f, 0.f, 0.f}, acc3 = {0.f, 0.f, 0.f, 0.f};
  float lacc = 0.f;
  const int goff = g * 8;

  // prefetch first chunk
  int j0 = w * 32 + goff;
  float4 e0 = *(const float4*)(eta + j0), e1 = *(const float4*)(eta + j0 + 4);
  float4 p0 = *(const float4*)(phi + j0), p1 = *(const float4*)(phi + j0 + 4);
  h8 b0 = *(const h8*)(HT + (0 * 16 + m) * NN + j0);
  h8 b1 = *(const h8*)(HT + (1 * 16 + m) * NN + j0);
  h8 b2 = *(const h8*)(HT + (2 * 16 + m) * NN + j0);
  h8 b3 = *(const h8*)(HT + (3 * 16 + m) * NN + j0);

  for (int jc = w; jc < 256; jc += 4) {
    const float ej[8] = {e0.x, e0.y, e0.z, e0.w, e1.x, e1.y, e1.z, e1.w};
    const float pj[8] = {p0.x, p0.y, p0.z, p0.w, p1.x, p1.y, p1.z, p1.w};
    const h8 cb0 = b0, cb1 = b1, cb2 = b2, cb3 = b3;
    // prefetch next chunk (clamped reload of first chunk on last iter)
    const int jn = (jc + 4 < 256) ? (jc + 4) : w;
    const int j0n = jn * 32 + goff;
    e0 = *(const float4*)(eta + j0n); e1 = *(const float4*)(eta + j0n + 4);
    p0 = *(const float4*)(phi + j0n); p1 = *(const float4*)(phi + j0n + 4);
    b0 = *(const h8*)(HT + (0 * 16 + m) * NN + j0n);
    b1 = *(const h8*)(HT + (1 * 16 + m) * NN + j0n);
    b2 = *(const h8*)(HT + (2 * 16 + m) * NN + j0n);
    b3 = *(const h8*)(HT + (3 * 16 + m) * NN + j0n);

    h8 afrag;
#pragma unroll
    for (int tt = 0; tt < 8; tt++) {
      const float de = my_eta - ej[tt];
      const float dpa = fabsf(my_phi - pj[tt]);
      const float wph = fminf(dpa, TWO_PI - dpa);          // exact wrap match
      const float dr2 = fmaf(de, de, wph * wph);
      const float a = __builtin_amdgcn_exp2f(c1 * dr2);    // exp(-alpha*dR2)
      const float pp = __builtin_amdgcn_exp2f(fmaf(a, L2E, -L2E)); // exp(a-1)
      if constexpr (NEED_L) lacc += pp;
      afrag[tt] = (_Float16)pp;
    }
    acc0 = __builtin_amdgcn_mfma_f32_16x16x32_f16(afrag, cb0, acc0, 0, 0, 0);
    acc1 = __builtin_amdgcn_mfma_f32_16x16x32_f16(afrag, cb1, acc1, 0, 0, 0);
    acc2 = __builtin_amdgcn_mfma_f32_16x16x32_f16(afrag, cb2, acc2, 0, 0, 0);
    acc3 = __builtin_amdgcn_mfma_f32_16x16x32_f16(afrag, cb3, acc3, 0, 0, 0);
  }

  // cross-wave reduction: D layout col=lane&15, row=(lane>>4)*4+reg
  __shared__ float partY[4][16][64];
  __shared__ float lred[4][4][16];
#pragma unroll
  for (int r = 0; r < 4; r++) {
    partY[w][g * 4 + r][0 * 16 + m] = acc0[r];
    partY[w][g * 4 + r][1 * 16 + m] = acc1[r];
    partY[w][g * 4 + r][2 * 16 + m] = acc2[r];
    partY[w][g * 4 + r][3 * 16 + m] = acc3[r];
  }
  if constexpr (NEED_L) lred[w][g][m] = lacc;
  __syncthreads();
#pragma unroll
  for (int k = 0; k < 4; k++) {
    const int e = tid + k * 256;
    const float v = partY[0][e >> 6][e & 63] + partY[1][e >> 6][e & 63] +
                    partY[2][e >> 6][e & 63] + partY[3][e >> 6][e & 63];
    Y[(i_base << 6) + e] = v;
  }
  if constexpr (NEED_L) {
    if (tid < 16) {
      float s = 0.f;
#pragma unroll
      for (int ww = 0; ww < 4; ww++)
#pragma unroll
        for (int gg = 0; gg < 4; gg++) s += lred[ww][gg][tid];
      lsum_out[i_base + tid] = s;
    }
  }
}

// ---------------------------------------------------------------------------
// Kernel B: row-local between layers:
// U = Y1/l + H1 ; Z = relu(U@wt1 + bs1) ; H2 = relu(Z@W2 + b2)  (+ f16 ᵀ copy)
// ---------------------------------------------------------------------------
__global__ __launch_bounds__(256) void mid_kernel(
    const float* __restrict__ Y1, const float* __restrict__ lsum,
    const float* __restrict__ H1, const float* __restrict__ wt1,
    const float* __restrict__ bs1, const float* __restrict__ W2,
    const float* __restrict__ b2, float* __restrict__ H2,
    _Float16* __restrict__ HT2)
{
  __shared__ float sA[64][65];   // wt1
  __shared__ float sB[64][65];   // W2
  __shared__ float U[64][65];
  __shared__ float sb2[64];
  const int t = threadIdx.x;
  for (int e = t; e < 4096; e += 256) {
    sA[e >> 6][e & 63] = wt1[e];
    sB[e >> 6][e & 63] = W2[e];
  }
  if (t < 64) sb2[t] = b2[t];
  const float bsv = bs1[0];
  const int i0 = blockIdx.x * 64;
  const int r = t >> 2, q = t & 3;
  const int i = i0 + r;
  const float rl = 1.0f / lsum[i];
#pragma unroll
  for (int cc = 0; cc < 16; cc++) {
    const int n = q * 16 + cc;
    U[r][n] = fmaf(Y1[i * 64 + n], rl, H1[i * 64 + n]);
  }
  __syncthreads();
  float z[16];
#pragma unroll
  for (int cc = 0; cc < 16; cc++) z[cc] = bsv;
  for (int k = 0; k < 64; k++) {
    const float uk = U[r][k];
#pragma unroll
    for (int cc = 0; cc < 16; cc++) z[cc] = fmaf(uk, sA[k][q * 16 + cc], z[cc]);
  }
  __syncthreads();
#pragma unroll
  for (int cc = 0; cc < 16; cc++) U[r][q * 16 + cc] = fmaxf(z[cc], 0.f);
  __syncthreads();
  float h[16];
#pragma unroll
  for (int cc = 0; cc < 16; cc++) h[cc] = sb2[q * 16 + cc];
  for (int k = 0; k < 64; k++) {
    const float uk = U[r][k];
#pragma unroll
    for (int cc = 0; cc < 16; cc++) h[cc] = fmaf(uk, sB[k][q * 16 + cc], h[cc]);
  }
  __syncthreads();
#pragma unroll
  for (int cc = 0; cc < 16; cc++) U[r][q * 16 + cc] = fmaxf(h[cc], 0.f);
  __syncthreads();
  for (int e = t; e < 4096; e += 256) H2[i0 * 64 + e] = U[e >> 6][e & 63];
  {
    const int n = t >> 2;
    const int ic = (t & 3) * 16;
    h8 v0, v1;
#pragma unroll
    for (int s = 0; s < 8; s++) v0[s] = (_Float16)U[ic + s][n];
#pragma unroll
    for (int s = 0; s < 8; s++) v1[s] = (_Float16)U[ic + 8 + s][n];
    *(h8*)(HT2 + n * NN + i0 + ic) = v0;
    *(h8*)(HT2 + n * NN + i0 + ic + 8) = v1;
  }
}

// ---------------------------------------------------------------------------
// Kernel C: V = relu((Y2/l + H2)@wt2 + bs2); block-local column sums; atomic
// accumulate into svec[64].
// ---------------------------------------------------------------------------
__global__ __launch_bounds__(256) void final_kernel(
    const float* __restrict__ Y2, const float* __restrict__ lsum,
    const float* __restrict__ H2, const float* __restrict__ wt2,
    const float* __restrict__ bs2, float* __restrict__ svec)
{
  __shared__ float sA[64][65];
  __shared__ float U[64][65];
  __shared__ float cred[4][64];
  const int t = threadIdx.x;
  for (int e = t; e < 4096; e += 256) sA[e >> 6][e & 63] = wt2[e];
  const float bsv = bs2[0];
  const int i0 = blockIdx.x * 64;
  const int r = t >> 2, q = t & 3;
  const int i = i0 + r;
  const float rl = 1.0f / lsum[i];
#pragma unroll
  for (int cc = 0; cc < 16; cc++) {
    const int n = q * 16 + cc;
    U[r][n] = fmaf(Y2[i * 64 + n], rl, H2[i * 64 + n]);
  }
  __syncthreads();
  float z[16];
#pragma unroll
  for (int cc = 0; cc < 16; cc++) z[cc] = bsv;
  for (int k = 0; k < 64; k++) {
    const float uk = U[r][k];
#pragma unroll
    for (int cc = 0; cc < 16; cc++) z[cc] = fmaf(uk, sA[k][q * 16 + cc], z[cc]);
  }
  __syncthreads();
#pragma unroll
  for (int cc = 0; cc < 16; cc++) U[r][q * 16 + cc] = fmaxf(z[cc], 0.f);
  __syncthreads();
  const int col = t & 63, rg = t >> 6;
  float ps = 0.f;
#pragma unroll
  for (int rr = 0; rr < 16; rr++) ps += U[rg * 16 + rr][col];
  cred[rg][col] = ps;
  __syncthreads();
  if (t < 64) {
    const float s = cred[0][t] + cred[1][t] + cred[2][t] + cred[3][t];
    atomicAdd(svec + t, s);
  }
}

// ---------------------------------------------------------------------------
// Kernel D: out = sigmoid(s @ Wl + bl)
// ---------------------------------------------------------------------------
__global__ void out_kernel(const float* __restrict__ svec,
                           const float* __restrict__ Wl,
                           const float* __restrict__ bl,
                           float* __restrict__ out)
{
  const int t = threadIdx.x;  // 64 threads
  float v = svec[t] * Wl[t];
#pragma unroll
  for (int off = 32; off > 0; off >>= 1) v += __shfl_down(v, off);
  if (t == 0) {
    const float logit = v + bl[0];
    out[0] = 1.0f / (1.0f + __builtin_amdgcn_exp2f(-logit * L2E));
  }
}

extern "C" void kernel_launch(void* const* d_in, const int* in_sizes, int n_in,
                              void* d_out, int out_size, void* d_ws,
                              size_t ws_size, hipStream_t stream)
{
  const float* x     = (const float*)d_in[0];
  const float* alpha = (const float*)d_in[1];
  const float* W1    = (const float*)d_in[2];
  const float* b1    = (const float*)d_in[3];
  const float* wt1   = (const float*)d_in[4];
  const float* bs1   = (const float*)d_in[5];
  const float* W2    = (const float*)d_in[6];
  const float* b2    = (const float*)d_in[7];
  const float* wt2   = (const float*)d_in[8];
  const float* bs2   = (const float*)d_in[9];
  const float* Wl    = (const float*)d_in[10];
  const float* bl    = (const float*)d_in[11];
  float* out = (float*)d_out;

  char* ws = (char*)d_ws;
  size_t off = 0;
  auto alloc = [&](size_t bytes) {
    void* p = ws + off;
    off = (off + bytes + 255) & ~(size_t)255;
    return p;
  };
  float* eta      = (float*)alloc(NN * 4);
  float* phi      = (float*)alloc(NN * 4);
  float* H1       = (float*)alloc(NN * 64 * 4);
  float* H2       = (float*)alloc(NN * 64 * 4);
  float* Y        = (float*)alloc(NN * 64 * 4);   // Y1, overwritten as Y2
  float* lsum     = (float*)alloc(NN * 4);
  _Float16* HT    = (_Float16*)alloc(NN * 64 * 2); // HT1, overwritten as HT2
  float* svec     = (float*)alloc(64 * 4);

  hipMemsetAsync(svec, 0, 64 * sizeof(float), stream);
  prep_kernel<<<128, 256, 0, stream>>>(x, W1, b1, eta, phi, H1, HT);
  attn_pass<true><<<512, 256, 0, stream>>>(eta, phi, HT, alpha, Y, lsum);
  mid_kernel<<<128, 256, 0, stream>>>(Y, lsum, H1, wt1, bs1, W2, b2, H2, HT);
  attn_pass<false><<<512, 256, 0, stream>>>(eta, phi, HT, alpha, Y, nullptr);
  final_kernel<<<128, 256, 0, stream>>>(Y, lsum, H2, wt2, bs2, svec);
  out_kernel<<<1, 64, 0, stream>>>(svec, Wl, bl, out);
}

// Round 2
// 192.012 us; speedup vs baseline: 1.3548x; 1.3548x over previous
//
#include <hip/hip_runtime.h>
#include <hip/hip_bf16.h>
#include <math.h>

#define NN 8192
#define L2E 1.44269504088896340736f
#define TWO_PI 6.28318530717958647693f

typedef _Float16 h8 __attribute__((ext_vector_type(8)));
typedef float f32x4 __attribute__((ext_vector_type(4)));

#define MFMA16(A, B, C) __builtin_amdgcn_mfma_f32_16x16x32_f16(A, B, C, 0, 0, 0)

// ---------------------------------------------------------------------------
// prep: eta_s = eta*sqrt(alpha*log2e), phi raw, H1 = relu(x@W1+b1) (f32 +
// f16-transposed), svec zeroed by block 0. 32 rows/block, grid 256.
// ---------------------------------------------------------------------------
__global__ __launch_bounds__(256) void prep_kernel(
    const float* __restrict__ x, const float* __restrict__ alpha,
    const float* __restrict__ W1, const float* __restrict__ b1,
    float* __restrict__ eta_s, float* __restrict__ phi,
    float* __restrict__ H1, _Float16* __restrict__ HT1,
    float* __restrict__ svec)
{
  __shared__ float sW[448];
  __shared__ float sb[64];
  __shared__ float T[32][65];
  const int t = threadIdx.x;
  if (blockIdx.x == 0 && t < 64) svec[t] = 0.f;
  for (int k = t; k < 448; k += 256) sW[k] = W1[k];
  if (t < 64) sb[t] = b1[t];
  const float s = sqrtf(alpha[0] * L2E);
  const int i0 = blockIdx.x * 32;
  const int r = t >> 3, q = t & 7;
  const int i = i0 + r;
  float xv[7];
#pragma unroll
  for (int k = 0; k < 7; k++) xv[k] = x[i * 7 + k];
  if (q == 0) { eta_s[i] = xv[1] * s; phi[i] = xv[2]; }
  __syncthreads();
#pragma unroll
  for (int c = 0; c < 8; c++) {
    const int n = q * 8 + c;
    float hv = sb[n];
#pragma unroll
    for (int k = 0; k < 7; k++) hv = fmaf(xv[k], sW[k * 64 + n], hv);
    T[r][n] = fmaxf(hv, 0.f);
  }
  __syncthreads();
  for (int e = t; e < 2048; e += 256) H1[i0 * 64 + e] = T[e >> 6][e & 63];
  const int n = t >> 2, sg = (t & 3) * 8;
  h8 v;
#pragma unroll
  for (int ss = 0; ss < 8; ss++) v[ss] = (_Float16)T[sg + ss][n];
  *(h8*)(HT1 + (size_t)n * NN + i0 + sg) = v;
}

// ---------------------------------------------------------------------------
// attn: 32-row tile (two 16-row MFMA tiles sharing B-frags), j split 4 ways
// across blocks, contiguous 512-wide j-range per wave. Grid = 256*4 = 1024.
// Per-wave-pair LDS reduction -> 8 global partials Ypart[8][N][64].
// ---------------------------------------------------------------------------
template <bool NEED_L>
__global__ __launch_bounds__(256, 4) void attn_pass(
    const float* __restrict__ eta_s, const float* __restrict__ phi,
    const _Float16* __restrict__ HT, const float* __restrict__ alpha,
    float* __restrict__ Ypart, float* __restrict__ lpart)
{
  const int tid = threadIdx.x;
  const int w = tid >> 6;
  const int lane = tid & 63;
  const int m = lane & 15;
  const int g = lane >> 4;
  const int tile = blockIdx.x >> 2;
  const int part = blockIdx.x & 3;
  const int i0 = tile << 5;
  const float s = sqrtf(alpha[0] * L2E);
  const float et0 = eta_s[i0 + m],      ph0 = phi[i0 + m];
  const float et1 = eta_s[i0 + 16 + m], ph1 = phi[i0 + 16 + m];

  f32x4 a00 = {0,0,0,0}, a01 = {0,0,0,0}, a02 = {0,0,0,0}, a03 = {0,0,0,0};
  f32x4 a10 = {0,0,0,0}, a11 = {0,0,0,0}, a12 = {0,0,0,0}, a13 = {0,0,0,0};
  float l0 = 0.f, l1 = 0.f;

  const int jb = part * 2048 + w * 512 + g * 8;
  const float* ep  = eta_s + jb;
  const float* php = phi + jb;
  const _Float16* h0p = HT + (size_t)(0 * 16 + m) * NN + jb;
  const _Float16* h1p = HT + (size_t)(1 * 16 + m) * NN + jb;
  const _Float16* h2p = HT + (size_t)(2 * 16 + m) * NN + jb;
  const _Float16* h3p = HT + (size_t)(3 * 16 + m) * NN + jb;

  float4 e0 = *(const float4*)ep,  e1 = *(const float4*)(ep + 4);
  float4 p0 = *(const float4*)php, p1 = *(const float4*)(php + 4);
  h8 b0 = *(const h8*)h0p, b1 = *(const h8*)h1p;
  h8 b2 = *(const h8*)h2p, b3 = *(const h8*)h3p;

  for (int it = 0; it < 16; ++it) {
    const float ea[8] = {e0.x, e0.y, e0.z, e0.w, e1.x, e1.y, e1.z, e1.w};
    const float pa[8] = {p0.x, p0.y, p0.z, p0.w, p1.x, p1.y, p1.z, p1.w};
    // issue next eta/phi loads (latency hidden by this iteration's scores)
    ep += 32; php += 32;
    e0 = *(const float4*)ep;  e1 = *(const float4*)(ep + 4);
    p0 = *(const float4*)php; p1 = *(const float4*)(php + 4);

    h8 af0, af1;
#pragma unroll
    for (int tt = 0; tt < 8; ++tt) {
      {
        const float dp = ph0 - pa[tt];
        const float wr = fminf(fabsf(dp), TWO_PI - fabsf(dp)) * s;
        const float de = et0 - ea[tt];
        const float r2 = fmaf(de, de, wr * wr);
        const float a  = __builtin_amdgcn_exp2f(-r2);
        const float P  = __builtin_amdgcn_exp2f(fmaf(a, L2E, -L2E));
        if constexpr (NEED_L) l0 += P;
        af0[tt] = (_Float16)P;
      }
      {
        const float dp = ph1 - pa[tt];
        const float wr = fminf(fabsf(dp), TWO_PI - fabsf(dp)) * s;
        const float de = et1 - ea[tt];
        const float r2 = fmaf(de, de, wr * wr);
        const float a  = __builtin_amdgcn_exp2f(-r2);
        const float P  = __builtin_amdgcn_exp2f(fmaf(a, L2E, -L2E));
        if constexpr (NEED_L) l1 += P;
        af1[tt] = (_Float16)P;
      }
    }
    a00 = MFMA16(af0, b0, a00); a01 = MFMA16(af0, b1, a01);
    a02 = MFMA16(af0, b2, a02); a03 = MFMA16(af0, b3, a03);
    a10 = MFMA16(af1, b0, a10); a11 = MFMA16(af1, b1, a11);
    a12 = MFMA16(af1, b2, a12); a13 = MFMA16(af1, b3, a13);
    // issue next B-frag loads (latency hidden by next iteration's scores)
    h0p += 32; h1p += 32; h2p += 32; h3p += 32;
    b0 = *(const h8*)h0p; b1 = *(const h8*)h1p;
    b2 = *(const h8*)h2p; b3 = *(const h8*)h3p;
  }

  // pairwise cross-wave reduction: waves {0,1}->half 0, {2,3}->half 1
  __shared__ float red[2][32][66];
  __shared__ float lred2[2][4][32];
  const int h = w >> 1;
  if ((w & 1) == 0) {
#pragma unroll
    for (int r = 0; r < 4; ++r) {
      red[h][g * 4 + r][m]      = a00[r]; red[h][g * 4 + r][16 + m] = a01[r];
      red[h][g * 4 + r][32 + m] = a02[r]; red[h][g * 4 + r][48 + m] = a03[r];
      red[h][16 + g * 4 + r][m]      = a10[r]; red[h][16 + g * 4 + r][16 + m] = a11[r];
      red[h][16 + g * 4 + r][32 + m] = a12[r]; red[h][16 + g * 4 + r][48 + m] = a13[r];
    }
    if constexpr (NEED_L) { lred2[h][g][m] = l0; lred2[h][g][16 + m] = l1; }
  }
  __syncthreads();
  if (w & 1) {
#pragma unroll
    for (int r = 0; r < 4; ++r) {
      red[h][g * 4 + r][m]      += a00[r]; red[h][g * 4 + r][16 + m] += a01[r];
      red[h][g * 4 + r][32 + m] += a02[r]; red[h][g * 4 + r][48 + m] += a03[r];
      red[h][16 + g * 4 + r][m]      += a10[r]; red[h][16 + g * 4 + r][16 + m] += a11[r];
      red[h][16 + g * 4 + r][32 + m] += a12[r]; red[h][16 + g * 4 + r][48 + m] += a13[r];
    }
    if constexpr (NEED_L) { lred2[h][g][m] += l0; lred2[h][g][16 + m] += l1; }
  }
  __syncthreads();
  const int pbase = part * 2;
#pragma unroll
  for (int hh = 0; hh < 2; ++hh) {
#pragma unroll
    for (int k = 0; k < 8; ++k) {
      const int e = tid + k * 256;
      Ypart[((size_t)(pbase + hh) * NN + i0 + (e >> 6)) * 64 + (e & 63)] =
          red[hh][e >> 6][e & 63];
    }
  }
  if constexpr (NEED_L) {
    if (tid < 64) {
      const int hh = tid >> 5, row = tid & 31;
      lpart[(size_t)(pbase + hh) * NN + i0 + row] =
          lred2[hh][0][row] + lred2[hh][1][row] +
          lred2[hh][2][row] + lred2[hh][3][row];
    }
  }
}

// ---------------------------------------------------------------------------
// mid: U = sum(Ypart)/l + H1 ; Z = relu(U@wt1+bs1) ; H2 = relu(Z@W2+b2)
// 32 rows/block, grid 256.
// ---------------------------------------------------------------------------
__global__ __launch_bounds__(256) void mid_kernel(
    const float* __restrict__ Yp, const float* __restrict__ lp,
    const float* __restrict__ H1, const float* __restrict__ wt1,
    const float* __restrict__ bs1, const float* __restrict__ W2,
    const float* __restrict__ b2, float* __restrict__ H2,
    _Float16* __restrict__ HT2)
{
  __shared__ float sA[64][64];
  __shared__ float sB[64][64];
  __shared__ float U[32][65];
  __shared__ float sb2v[64];
  const int t = threadIdx.x;
  for (int e = t; e < 4096; e += 256) {
    sA[e >> 6][e & 63] = wt1[e];
    sB[e >> 6][e & 63] = W2[e];
  }
  if (t < 64) sb2v[t] = b2[t];
  const float bsv = bs1[0];
  const int i0 = blockIdx.x * 32;
  const int r = t >> 3, q = t & 7;
  const int i = i0 + r;
  float l = 0.f;
#pragma unroll
  for (int p = 0; p < 8; ++p) l += lp[(size_t)p * NN + i];
  const float rl = 1.0f / l;
  f32x4 ya = {0,0,0,0}, yb = {0,0,0,0};
#pragma unroll
  for (int p = 0; p < 8; ++p) {
    ya += *(const f32x4*)(Yp + ((size_t)p * NN + i) * 64 + q * 8);
    yb += *(const f32x4*)(Yp + ((size_t)p * NN + i) * 64 + q * 8 + 4);
  }
  const f32x4 h1a = *(const f32x4*)(H1 + (size_t)i * 64 + q * 8);
  const f32x4 h1b = *(const f32x4*)(H1 + (size_t)i * 64 + q * 8 + 4);
#pragma unroll
  for (int c = 0; c < 4; ++c) {
    U[r][q * 8 + c]     = fmaf(ya[c], rl, h1a[c]);
    U[r][q * 8 + 4 + c] = fmaf(yb[c], rl, h1b[c]);
  }
  __syncthreads();
  float z[8];
#pragma unroll
  for (int c = 0; c < 8; ++c) z[c] = bsv;
  for (int k = 0; k < 64; ++k) {
    const float uk = U[r][k];
#pragma unroll
    for (int c = 0; c < 8; ++c) z[c] = fmaf(uk, sA[k][q * 8 + c], z[c]);
  }
  __syncthreads();
#pragma unroll
  for (int c = 0; c < 8; ++c) U[r][q * 8 + c] = fmaxf(z[c], 0.f);
  __syncthreads();
  float hv[8];
#pragma unroll
  for (int c = 0; c < 8; ++c) hv[c] = sb2v[q * 8 + c];
  for (int k = 0; k < 64; ++k) {
    const float uk = U[r][k];
#pragma unroll
    for (int c = 0; c < 8; ++c) hv[c] = fmaf(uk, sB[k][q * 8 + c], hv[c]);
  }
  __syncthreads();
#pragma unroll
  for (int c = 0; c < 8; ++c) U[r][q * 8 + c] = fmaxf(hv[c], 0.f);
  __syncthreads();
  for (int e = t; e < 2048; e += 256) H2[i0 * 64 + e] = U[e >> 6][e & 63];
  const int n = t >> 2, sg = (t & 3) * 8;
  h8 v;
#pragma unroll
  for (int ss = 0; ss < 8; ss++) v[ss] = (_Float16)U[sg + ss][n];
  *(h8*)(HT2 + (size_t)n * NN + i0 + sg) = v;
}

// ---------------------------------------------------------------------------
// final: V = relu((sum(Ypart)/l + H2)@wt2 + bs2); column sums -> atomicAdd
// ---------------------------------------------------------------------------
__global__ __launch_bounds__(256) void final_kernel(
    const float* __restrict__ Yp, const float* __restrict__ lp,
    const float* __restrict__ H2, const float* __restrict__ wt2,
    const float* __restrict__ bs2, float* __restrict__ svec)
{
  __shared__ float sA[64][64];
  __shared__ float U[32][65];
  __shared__ float cred[4][64];
  const int t = threadIdx.x;
  for (int e = t; e < 4096; e += 256) sA[e >> 6][e & 63] = wt2[e];
  const float bsv = bs2[0];
  const int i0 = blockIdx.x * 32;
  const int r = t >> 3, q = t & 7;
  const int i = i0 + r;
  float l = 0.f;
#pragma unroll
  for (int p = 0; p < 8; ++p) l += lp[(size_t)p * NN + i];
  const float rl = 1.0f / l;
  f32x4 ya = {0,0,0,0}, yb = {0,0,0,0};
#pragma unroll
  for (int p = 0; p < 8; ++p) {
    ya += *(const f32x4*)(Yp + ((size_t)p * NN + i) * 64 + q * 8);
    yb += *(const f32x4*)(Yp + ((size_t)p * NN + i) * 64 + q * 8 + 4);
  }
  const f32x4 h2a = *(const f32x4*)(H2 + (size_t)i * 64 + q * 8);
  const f32x4 h2b = *(const f32x4*)(H2 + (size_t)i * 64 + q * 8 + 4);
#pragma unroll
  for (int c = 0; c < 4; ++c) {
    U[r][q * 8 + c]     = fmaf(ya[c], rl, h2a[c]);
    U[r][q * 8 + 4 + c] = fmaf(yb[c], rl, h2b[c]);
  }
  __syncthreads();
  float z[8];
#pragma unroll
  for (int c = 0; c < 8; ++c) z[c] = bsv;
  for (int k = 0; k < 64; ++k) {
    const float uk = U[r][k];
#pragma unroll
    for (int c = 0; c < 8; ++c) z[c] = fmaf(uk, sA[k][q * 8 + c], z[c]);
  }
  __syncthreads();
#pragma unroll
  for (int c = 0; c < 8; ++c) U[r][q * 8 + c] = fmaxf(z[c], 0.f);
  __syncthreads();
  const int col = t & 63, rg = t >> 6;
  float ps = 0.f;
#pragma unroll
  for (int rr = 0; rr < 8; rr++) ps += U[rg * 8 + rr][col];
  cred[rg][col] = ps;
  __syncthreads();
  if (t < 64)
    atomicAdd(svec + t, cred[0][t] + cred[1][t] + cred[2][t] + cred[3][t]);
}

__global__ void out_kernel(const float* __restrict__ svec,
                           const float* __restrict__ Wl,
                           const float* __restrict__ bl,
                           float* __restrict__ out)
{
  const int t = threadIdx.x;  // 64 threads
  float v = svec[t] * Wl[t];
#pragma unroll
  for (int off = 32; off > 0; off >>= 1) v += __shfl_down(v, off);
  if (t == 0) {
    const float logit = v + bl[0];
    out[0] = 1.0f / (1.0f + __builtin_amdgcn_exp2f(-logit * L2E));
  }
}

extern "C" void kernel_launch(void* const* d_in, const int* in_sizes, int n_in,
                              void* d_out, int out_size, void* d_ws,
                              size_t ws_size, hipStream_t stream)
{
  const float* x     = (const float*)d_in[0];
  const float* alpha = (const float*)d_in[1];
  const float* W1    = (const float*)d_in[2];
  const float* b1    = (const float*)d_in[3];
  const float* wt1   = (const float*)d_in[4];
  const float* bs1   = (const float*)d_in[5];
  const float* W2    = (const float*)d_in[6];
  const float* b2    = (const float*)d_in[7];
  const float* wt2   = (const float*)d_in[8];
  const float* bs2   = (const float*)d_in[9];
  const float* Wl    = (const float*)d_in[10];
  const float* bl    = (const float*)d_in[11];
  float* out = (float*)d_out;

  char* ws = (char*)d_ws;
  size_t off = 0;
  auto alloc = [&](size_t bytes) {
    void* p = ws + off;
    off = (off + bytes + 255) & ~(size_t)255;
    return p;
  };
  float* eta_s = (float*)alloc(NN * 4 + 256);       // +over-read pad
  float* phi   = (float*)alloc(NN * 4 + 256);
  float* H1    = (float*)alloc((size_t)NN * 64 * 4);
  float* H2    = (float*)alloc((size_t)NN * 64 * 4);
  float* Ypart = (float*)alloc((size_t)8 * NN * 64 * 4);   // 16 MB
  float* lpart = (float*)alloc((size_t)8 * NN * 4);
  _Float16* HT = (_Float16*)alloc((size_t)NN * 64 * 2 + 512);
  float* svec  = (float*)alloc(64 * 4);

  prep_kernel<<<256, 256, 0, stream>>>(x, alpha, W1, b1, eta_s, phi, H1, HT, svec);
  attn_pass<true><<<1024, 256, 0, stream>>>(eta_s, phi, HT, alpha, Ypart, lpart);
  mid_kernel<<<256, 256, 0, stream>>>(Ypart, lpart, H1, wt1, bs1, W2, b2, H2, HT);
  attn_pass<false><<<1024, 256, 0, stream>>>(eta_s, phi, HT, alpha, Ypart, nullptr);
  final_kernel<<<256, 256, 0, stream>>>(Ypart, lpart, H2, wt2, bs2, svec);
  out_kernel<<<1, 64, 0, stream>>>(svec, Wl, bl, out);
}